// Round 8
// baseline (370.131 us; speedup 1.0000x reference)
//
#include <hip/hip_runtime.h>

#define N_NODES 50000
#define N_EDGES 800000
#define SCAN_NB ((N_NODES + 255) / 256)   // 196
#define NCHUNK 128
#define NRANGE 4
#define RNODES (N_NODES / NRANGE)         // 12500
#define CEDGES (N_EDGES / NCHUNK)         // 6250

typedef __attribute__((ext_vector_type(8))) short short8;
typedef __attribute__((ext_vector_type(4))) float f32x4;

struct WPtrs { const float* p[12]; };

__device__ inline unsigned short f2b(float f) {
    union { float f; unsigned u; } c; c.f = f;
    return (unsigned short)((c.u + 0x7FFFu + ((c.u >> 16) & 1u)) >> 16);
}
__device__ inline float b2f(unsigned short h) {
    union { unsigned u; float f; } c; c.u = ((unsigned)h) << 16;
    return c.f;
}

// ---------------------------------------------------------------------------
// K1: partial histograms (u16). Block = (chunk, range). LDS atomics only.
__global__ __launch_bounds__(256) void histp_kernel(const int* __restrict__ dst,
                                                    unsigned short* __restrict__ hist_part) {
    __shared__ int h[RNODES];
    const int chunk = blockIdx.x >> 2;
    const int range = blockIdx.x & 3;
    const int nbase = range * RNODES;
    for (int i = threadIdx.x; i < RNODES; i += 256) h[i] = 0;
    __syncthreads();
    const int* dp = dst + chunk * CEDGES;
    for (int i = threadIdx.x; i < CEDGES; i += 256) {
        int d = dp[i] - nbase;
        if ((unsigned)d < (unsigned)RNODES) atomicAdd(&h[d], 1);
    }
    __syncthreads();
    unsigned short* out = hist_part + (long)chunk * N_NODES + nbase;
    for (int i = threadIdx.x; i < RNODES; i += 256) out[i] = (unsigned short)h[i];
}

// ---------------------------------------------------------------------------
// K2 (fused chunkscan + scanA): per node, exclusive scan across chunks
// (in place, u16), then block-scan the node totals -> off partials + bsum.
__global__ __launch_bounds__(256) void scanA2_kernel(unsigned short* __restrict__ hist_part,
                                                     int* __restrict__ off,
                                                     int* __restrict__ bsum) {
    __shared__ int tmp[256];
    const int t = threadIdx.x;
    const int node = blockIdx.x * 256 + t;
    int run = 0;
    if (node < N_NODES) {
        #pragma unroll
        for (int c = 0; c < NCHUNK; ++c) {
            unsigned short* p = hist_part + (long)c * N_NODES + node;
            int v = *p;
            *p = (unsigned short)run;
            run += v;
        }
    }
    int v = run;
    tmp[t] = v;
    __syncthreads();
    #pragma unroll
    for (int d = 1; d < 256; d <<= 1) {
        int u = (t >= d) ? tmp[t - d] : 0;
        __syncthreads();
        tmp[t] += u;
        __syncthreads();
    }
    if (node < N_NODES) off[node] = tmp[t] - v;
    if (t == 255) bsum[blockIdx.x] = tmp[255];
}

__global__ __launch_bounds__(256) void scanB_kernel(const int* __restrict__ bsum,
                                                    int* __restrict__ boff,
                                                    int* __restrict__ off) {
    __shared__ int tmp[256];
    const int t = threadIdx.x;
    int v = (t < SCAN_NB) ? bsum[t] : 0;
    tmp[t] = v;
    __syncthreads();
    #pragma unroll
    for (int d = 1; d < 256; d <<= 1) {
        int u = (t >= d) ? tmp[t - d] : 0;
        __syncthreads();
        tmp[t] += u;
        __syncthreads();
    }
    if (t < SCAN_NB) boff[t] = tmp[t] - v;
    if (t == 255) off[N_NODES] = tmp[255];
}

__global__ __launch_bounds__(256) void scanC_kernel(const int* __restrict__ boff,
                                                    int* __restrict__ off) {
    int i = blockIdx.x * 256 + threadIdx.x;
    if (i < N_NODES) off[i] += boff[blockIdx.x];
}

// ---------------------------------------------------------------------------
// K3: fill csr. Cursor = off[d] + base[chunk][d] in LDS; LDS atomics rank
// edges; plain global stores only (L2-absorbed).
__global__ __launch_bounds__(256) void fillp_kernel(const int* __restrict__ src,
                                                    const int* __restrict__ dst,
                                                    const int* __restrict__ off,
                                                    const unsigned short* __restrict__ hist_part,
                                                    int* __restrict__ csr) {
    __shared__ int cur[RNODES];
    const int chunk = blockIdx.x >> 2;
    const int range = blockIdx.x & 3;
    const int nbase = range * RNODES;
    const unsigned short* bp = hist_part + (long)chunk * N_NODES + nbase;
    const int* op = off + nbase;
    for (int i = threadIdx.x; i < RNODES; i += 256) cur[i] = op[i] + (int)bp[i];
    __syncthreads();
    const int* dp = dst + chunk * CEDGES;
    const int* sp = src + chunk * CEDGES;
    for (int i = threadIdx.x; i < CEDGES; i += 256) {
        int d = dp[i] - nbase;
        if ((unsigned)d < (unsigned)RNODES) {
            int pos = atomicAdd(&cur[d], 1);
            csr[pos] = sp[i];
        }
    }
}

// ---------------------------------------------------------------------------
// Pack ALL layers' weights into B-fragment order (bf16). Grid = 3*16 blocks.
__global__ __launch_bounds__(256) void pack_w_all_kernel(WPtrs wp,
                                                         unsigned short* __restrict__ Wp)
{
    const int layer = blockIdx.x >> 4;
    const int ct = blockIdx.x & 15;
    const float* W = wp.p[layer * 4 + (ct >> 2)];
    const int colb = (ct & 3) * 16;
    for (int local = threadIdx.x; local < 1024; local += 256) {
        int j = local & 7, lane = (local >> 3) & 63, s = local >> 9;
        int k = s * 32 + (lane >> 4) * 8 + j;
        int col = colb + (lane & 15);
        Wp[layer * 16384 + ct * 1024 + local] = f2b(W[k * 64 + col]);
    }
}

// ---------------------------------------------------------------------------
// [a|b|c] = h @ [W1|W2|W3] + [b1|0|b3], bf16 MFMA, no LDS.
// hf32 != null (layer 0): read fp32 x, cast in-register.
__global__ __launch_bounds__(256) void gemm3_mfma_kernel(
    const unsigned short* __restrict__ hbf, const float* __restrict__ hf32,
    const unsigned short* __restrict__ Wp,
    const float* __restrict__ b1, const float* __restrict__ b3,
    unsigned short* __restrict__ abf, unsigned short* __restrict__ bbf,
    unsigned short* __restrict__ cbf, int n)
{
    const int t = threadIdx.x;
    const int lane = t & 63;
    const int quad = lane >> 4, lm = lane & 15;
    const int row_base = blockIdx.x * 64 + (t >> 6) * 16;

    int arow = min(row_base + lm, n - 1);
    short8 a0, a1;
    if (hf32) {
        const float* hrow = hf32 + (long)arow * 64;
        #pragma unroll
        for (int j = 0; j < 8; ++j) {
            a0[j] = (short)f2b(hrow[quad * 8 + j]);
            a1[j] = (short)f2b(hrow[32 + quad * 8 + j]);
        }
    } else {
        const unsigned short* hrow = hbf + (long)arow * 64;
        a0 = *(const short8*)(hrow + quad * 8);
        a1 = *(const short8*)(hrow + 32 + quad * 8);
    }

    const short8* wp = (const short8*)Wp;
    f32x4 acc[12];
    #pragma unroll
    for (int ct = 0; ct < 12; ++ct) {
        f32x4 z = {0.f, 0.f, 0.f, 0.f};
        short8 w0 = wp[(ct * 2 + 0) * 64 + lane];
        short8 w1 = wp[(ct * 2 + 1) * 64 + lane];
        z = __builtin_amdgcn_mfma_f32_16x16x32_bf16(a0, w0, z, 0, 0, 0);
        z = __builtin_amdgcn_mfma_f32_16x16x32_bf16(a1, w1, z, 0, 0, 0);
        acc[ct] = z;
    }

    #pragma unroll
    for (int ct = 0; ct < 12; ++ct) {
        int col = ct * 16 + lm;
        float bias = 0.f;
        unsigned short* dstp;
        int lcol;
        if (ct < 4)       { bias = b1[col];        dstp = abf; lcol = col; }
        else if (ct < 8)  {                        dstp = bbf; lcol = col - 64; }
        else              { bias = b3[col - 128];  dstp = cbf; lcol = col - 128; }
        #pragma unroll
        for (int r = 0; r < 4; ++r) {
            int g = row_base + quad * 4 + r;
            if (g < n) dstp[(long)g * 64 + lcol] = f2b(acc[ct][r] + bias);
        }
    }
}

// ---------------------------------------------------------------------------
// Fused gather + combine. Block = 64 nodes, 4 waves; wave w gathers its own
// 16 nodes (vectorized: lane = edge-group g, feature-quad f; 512 B/load
// instr), computes P = S - deg*b + c in-register, parks bf16 in LDS (pitch
// 72 -> only free 2-way conflicts), then MFMAs its own 16 rows with Wl.
__global__ __launch_bounds__(256) void gather_combine_kernel(
    const int* __restrict__ off, const int* __restrict__ csr,
    const unsigned short* __restrict__ abf,
    const unsigned short* __restrict__ bbf,
    const unsigned short* __restrict__ cbf,
    const unsigned short* __restrict__ Wp, const float* __restrict__ bl,
    float* __restrict__ out_f, unsigned short* __restrict__ out_b,
    int n, int last)
{
    __shared__ unsigned short P[64][72];   // 9 KB
    const int t = threadIdx.x;
    const int w = t >> 6;
    const int lane = t & 63;
    const int g = lane >> 4;
    const int f = (lane & 15) * 4;
    const int tile0 = blockIdx.x * 64;
    const int row_base = tile0 + w * 16;

    for (int i = 0; i < 16; ++i) {
        int nd = min(row_base + i, n - 1);
        int beg = off[nd], end = off[nd + 1];
        float deg = (float)(end - beg);
        float ax = 0.f, ay = 0.f, az = 0.f, aw = 0.f;
        int j = beg;
        for (; j + 8 <= end; j += 8) {
            int s0 = csr[j + g], s1 = csr[j + 4 + g];
            ushort4 v0 = *(const ushort4*)(abf + (long)s0 * 64 + f);
            ushort4 v1 = *(const ushort4*)(abf + (long)s1 * 64 + f);
            ax += b2f(v0.x) + b2f(v1.x);
            ay += b2f(v0.y) + b2f(v1.y);
            az += b2f(v0.z) + b2f(v1.z);
            aw += b2f(v0.w) + b2f(v1.w);
        }
        for (; j < end; j += 4) {
            int jj = j + g;
            if (jj < end) {
                int s0 = csr[jj];
                ushort4 v0 = *(const ushort4*)(abf + (long)s0 * 64 + f);
                ax += b2f(v0.x); ay += b2f(v0.y); az += b2f(v0.z); aw += b2f(v0.w);
            }
        }
        #pragma unroll
        for (int m = 16; m < 64; m <<= 1) {
            ax += __shfl_xor(ax, m, 64);
            ay += __shfl_xor(ay, m, 64);
            az += __shfl_xor(az, m, 64);
            aw += __shfl_xor(aw, m, 64);
        }
        if (g == 0) {
            ushort4 bv = *(const ushort4*)(bbf + (long)nd * 64 + f);
            ushort4 cv = *(const ushort4*)(cbf + (long)nd * 64 + f);
            ushort4 pv;
            pv.x = f2b(ax - deg * b2f(bv.x) + b2f(cv.x));
            pv.y = f2b(ay - deg * b2f(bv.y) + b2f(cv.y));
            pv.z = f2b(az - deg * b2f(bv.z) + b2f(cv.z));
            pv.w = f2b(aw - deg * b2f(bv.w) + b2f(cv.w));
            *(ushort4*)&P[w * 16 + i][f] = pv;
        }
    }
    __syncthreads();

    // MFMA over this wave's 16 rows
    const int quad = g, lm = lane & 15;
    short8 p0 = *(const short8*)&P[w * 16 + lm][quad * 8];
    short8 p1 = *(const short8*)&P[w * 16 + lm][32 + quad * 8];

    const short8* wp = (const short8*)Wp;
    #pragma unroll
    for (int ct = 0; ct < 4; ++ct) {
        f32x4 z = {0.f, 0.f, 0.f, 0.f};
        short8 w0 = wp[((12 + ct) * 2 + 0) * 64 + lane];
        short8 w1 = wp[((12 + ct) * 2 + 1) * 64 + lane];
        z = __builtin_amdgcn_mfma_f32_16x16x32_bf16(p0, w0, z, 0, 0, 0);
        z = __builtin_amdgcn_mfma_f32_16x16x32_bf16(p1, w1, z, 0, 0, 0);
        int col = ct * 16 + lm;
        float bias = bl[col];
        #pragma unroll
        for (int r = 0; r < 4; ++r) {
            int gr = row_base + quad * 4 + r;
            if (gr < n) {
                float v = fmaxf(z[r] + bias, 0.0f);
                if (last) out_f[(long)gr * 64 + col] = v;
                else      out_b[(long)gr * 64 + col] = f2b(v);
            }
        }
    }
}

// ---------------------------------------------------------------------------
extern "C" void kernel_launch(void* const* d_in, const int* in_sizes, int n_in,
                              void* d_out, int out_size, void* d_ws, size_t ws_size,
                              hipStream_t stream) {
    const float* x  = (const float*)d_in[0];
    const int*   ei = (const int*)d_in[1];
    const int*   src = ei;
    const int*   dst = ei + N_EDGES;

    char* wsb = (char*)d_ws;
    unsigned short* hist_part = (unsigned short*)(wsb);         // 12.8 MB
    unsigned short* abf  = (unsigned short*)(wsb + 12800000);   // 6.4 MB
    unsigned short* bbf  = (unsigned short*)(wsb + 19200000);   // 6.4 MB
    unsigned short* cbf  = (unsigned short*)(wsb + 25600000);   // 6.4 MB
    unsigned short* h1   = (unsigned short*)(wsb + 32000000);   // 6.4 MB
    unsigned short* Wp   = (unsigned short*)(wsb + 44800000);   // 3 * 32 KB
    int* off  = (int*)(wsb + 44900000);                         // N_NODES + 1
    int* bsum = off + N_NODES + 1;
    int* boff = bsum + SCAN_NB;
    int* csr  = boff + SCAN_NB;                                 // N_EDGES

    const int NBLK = (N_NODES + 63) / 64;    // 782

    // ---- CSR build: zero global atomics, 5 launches ----
    histp_kernel<<<NCHUNK * NRANGE, 256, 0, stream>>>(dst, hist_part);
    scanA2_kernel<<<SCAN_NB, 256, 0, stream>>>(hist_part, off, bsum);
    scanB_kernel<<<1, 256, 0, stream>>>(bsum, boff, off);
    scanC_kernel<<<SCAN_NB, 256, 0, stream>>>(boff, off);
    fillp_kernel<<<NCHUNK * NRANGE, 256, 0, stream>>>(src, dst, off, hist_part, csr);

    // ---- weight packing: one kernel, all layers ----
    WPtrs wps;
    for (int l = 0; l < 3; ++l) {
        int base = 2 + l * 7;
        wps.p[l * 4 + 0] = (const float*)d_in[base + 0];
        wps.p[l * 4 + 1] = (const float*)d_in[base + 2];
        wps.p[l * 4 + 2] = (const float*)d_in[base + 3];
        wps.p[l * 4 + 3] = (const float*)d_in[base + 5];
    }
    pack_w_all_kernel<<<48, 256, 0, stream>>>(wps, Wp);

    const unsigned short* hin = nullptr;   // layer 0 reads x directly
    for (int l = 0; l < 3; ++l) {
        int base = 2 + l * 7;
        const float* b1 = (const float*)d_in[base + 1];
        const float* b3 = (const float*)d_in[base + 4];
        const float* bl = (const float*)d_in[base + 6];
        const unsigned short* wp = Wp + l * 16384;

        gemm3_mfma_kernel<<<NBLK, 256, 0, stream>>>(
            hin, (l == 0) ? x : nullptr, wp, b1, b3, abf, bbf, cbf, N_NODES);

        int last = (l == 2);
        gather_combine_kernel<<<NBLK, 256, 0, stream>>>(
            off, csr, abf, bbf, cbf, wp, bl,
            (float*)d_out, h1, N_NODES, last);
        hin = h1;
    }
}

// Round 9
// 276.571 us; speedup vs baseline: 1.3383x; 1.3383x over previous
//
#include <hip/hip_runtime.h>

#define N_NODES 50000
#define N_EDGES 800000
#define SCAN_NB ((N_NODES + 255) / 256)   // 196
#define NCHUNK 128
#define NRANGE 4
#define RNODES (N_NODES / NRANGE)         // 12500
#define CEDGES (N_EDGES / NCHUNK)         // 6250

typedef __attribute__((ext_vector_type(8))) short short8;
typedef __attribute__((ext_vector_type(4))) float f32x4;

struct LPtrs { const float *W1, *W2, *W3, *Wl, *b1, *b3, *bl; };
struct AllPtrs { LPtrs l[3]; };

__device__ inline unsigned short f2b(float f) {
    union { float f; unsigned u; } c; c.f = f;
    return (unsigned short)((c.u + 0x7FFFu + ((c.u >> 16) & 1u)) >> 16);
}
__device__ inline float b2f(unsigned short h) {
    union { unsigned u; float f; } c; c.u = ((unsigned)h) << 16;
    return c.f;
}

// ---------------------------------------------------------------------------
// K1: partial histograms (u16). Block = (chunk, range). LDS atomics only.
__global__ __launch_bounds__(256) void histp_kernel(const int* __restrict__ dst,
                                                    unsigned short* __restrict__ hist_part) {
    __shared__ int h[RNODES];
    const int chunk = blockIdx.x >> 2;
    const int range = blockIdx.x & 3;
    const int nbase = range * RNODES;
    for (int i = threadIdx.x; i < RNODES; i += 256) h[i] = 0;
    __syncthreads();
    const int* dp = dst + chunk * CEDGES;
    for (int i = threadIdx.x; i < CEDGES; i += 256) {
        int d = dp[i] - nbase;
        if ((unsigned)d < (unsigned)RNODES) atomicAdd(&h[d], 1);
    }
    __syncthreads();
    unsigned short* out = hist_part + (long)chunk * N_NODES + nbase;
    for (int i = threadIdx.x; i < RNODES; i += 256) out[i] = (unsigned short)h[i];
}

// ---------------------------------------------------------------------------
// K2 (fused chunkscan + scanA): per node, exclusive scan across chunks
// (in place, u16), then block-scan the node totals -> off partials + bsum.
__global__ __launch_bounds__(256) void scanA2_kernel(unsigned short* __restrict__ hist_part,
                                                     int* __restrict__ off,
                                                     int* __restrict__ bsum) {
    __shared__ int tmp[256];
    const int t = threadIdx.x;
    const int node = blockIdx.x * 256 + t;
    int run = 0;
    if (node < N_NODES) {
        #pragma unroll
        for (int c = 0; c < NCHUNK; ++c) {
            unsigned short* p = hist_part + (long)c * N_NODES + node;
            int v = *p;
            *p = (unsigned short)run;
            run += v;
        }
    }
    int v = run;
    tmp[t] = v;
    __syncthreads();
    #pragma unroll
    for (int d = 1; d < 256; d <<= 1) {
        int u = (t >= d) ? tmp[t - d] : 0;
        __syncthreads();
        tmp[t] += u;
        __syncthreads();
    }
    if (node < N_NODES) off[node] = tmp[t] - v;
    if (t == 255) bsum[blockIdx.x] = tmp[255];
}

__global__ __launch_bounds__(256) void scanB_kernel(const int* __restrict__ bsum,
                                                    int* __restrict__ boff,
                                                    int* __restrict__ off) {
    __shared__ int tmp[256];
    const int t = threadIdx.x;
    int v = (t < SCAN_NB) ? bsum[t] : 0;
    tmp[t] = v;
    __syncthreads();
    #pragma unroll
    for (int d = 1; d < 256; d <<= 1) {
        int u = (t >= d) ? tmp[t - d] : 0;
        __syncthreads();
        tmp[t] += u;
        __syncthreads();
    }
    if (t < SCAN_NB) boff[t] = tmp[t] - v;
    if (t == 255) off[N_NODES] = tmp[255];
}

__global__ __launch_bounds__(256) void scanC_kernel(const int* __restrict__ boff,
                                                    int* __restrict__ off) {
    int i = blockIdx.x * 256 + threadIdx.x;
    if (i < N_NODES) off[i] += boff[blockIdx.x];
}

// ---------------------------------------------------------------------------
// K3: fill csr. Cursor = off[d] + base[chunk][d] in LDS; LDS atomics rank
// edges; plain global stores only (L2-absorbed).
__global__ __launch_bounds__(256) void fillp_kernel(const int* __restrict__ src,
                                                    const int* __restrict__ dst,
                                                    const int* __restrict__ off,
                                                    const unsigned short* __restrict__ hist_part,
                                                    int* __restrict__ csr) {
    __shared__ int cur[RNODES];
    const int chunk = blockIdx.x >> 2;
    const int range = blockIdx.x & 3;
    const int nbase = range * RNODES;
    const unsigned short* bp = hist_part + (long)chunk * N_NODES + nbase;
    const int* op = off + nbase;
    for (int i = threadIdx.x; i < RNODES; i += 256) cur[i] = op[i] + (int)bp[i];
    __syncthreads();
    const int* dp = dst + chunk * CEDGES;
    const int* sp = src + chunk * CEDGES;
    for (int i = threadIdx.x; i < CEDGES; i += 256) {
        int d = dp[i] - nbase;
        if ((unsigned)d < (unsigned)RNODES) {
            int pos = atomicAdd(&cur[d], 1);
            csr[pos] = sp[i];
        }
    }
}

// ---------------------------------------------------------------------------
// Precompute: Wml = Wm @ Wl (m=1,2,3) packed into B-fragment bf16 layout,
// plus row1 = b1@Wl and row3 = b3@Wl + bl per layer.
// Grid = 3 layers x 12 col-tiles.
__global__ __launch_bounds__(256) void pack_mm_kernel(AllPtrs ap,
                                                      unsigned short* __restrict__ Wp,
                                                      float* __restrict__ rows)
{
    __shared__ float sW[64][65];   // Wm, padded
    __shared__ float sL[64][17];   // Wl[:, colb..colb+15], padded
    const int layer = blockIdx.x / 12;
    const int ct = blockIdx.x % 12;
    LPtrs L = ap.l[layer];
    const float* Wm = (ct < 4) ? L.W1 : (ct < 8) ? L.W2 : L.W3;
    const int colb = (ct & 3) * 16;

    for (int i = threadIdx.x; i < 64 * 64; i += 256) sW[i >> 6][i & 63] = Wm[i];
    for (int i = threadIdx.x; i < 64 * 16; i += 256) {
        int q = i >> 4, c = i & 15;
        sL[q][c] = L.Wl[q * 64 + colb + c];
    }
    __syncthreads();

    for (int local = threadIdx.x; local < 1024; local += 256) {
        int j = local & 7, lane = (local >> 3) & 63, s = local >> 9;
        int k = s * 32 + (lane >> 4) * 8 + j;
        int c = lane & 15;
        float acc = 0.f;
        #pragma unroll 8
        for (int q = 0; q < 64; ++q) acc += sW[k][q] * sL[q][c];
        Wp[layer * 12288 + ct * 1024 + local] = f2b(acc);
    }

    if (ct == 0 && threadIdx.x < 64) {
        int col = threadIdx.x;
        float r1 = 0.f, r3 = 0.f;
        for (int q = 0; q < 64; ++q) {
            float wl = L.Wl[q * 64 + col];
            r1 += L.b1[q] * wl;
            r3 += L.b3[q] * wl;
        }
        rows[layer * 128 + col] = r1;
        rows[layer * 128 + 64 + col] = r3 + L.bl[col];
    }
}

// ---------------------------------------------------------------------------
// [a'|u|v] = h @ [W1l|W2l|W3l], bf16 MFMA, no LDS, no biases.
// hf32 != null (layer 0): read fp32 x, cast in-register.
__global__ __launch_bounds__(256) void gemm3_mfma_kernel(
    const unsigned short* __restrict__ hbf, const float* __restrict__ hf32,
    const unsigned short* __restrict__ Wp,
    unsigned short* __restrict__ abf, unsigned short* __restrict__ ubf,
    unsigned short* __restrict__ vbf, int n)
{
    const int t = threadIdx.x;
    const int lane = t & 63;
    const int quad = lane >> 4, lm = lane & 15;
    const int row_base = blockIdx.x * 64 + (t >> 6) * 16;

    int arow = min(row_base + lm, n - 1);
    short8 a0, a1;
    if (hf32) {
        const float* hrow = hf32 + (long)arow * 64;
        #pragma unroll
        for (int j = 0; j < 8; ++j) {
            a0[j] = (short)f2b(hrow[quad * 8 + j]);
            a1[j] = (short)f2b(hrow[32 + quad * 8 + j]);
        }
    } else {
        const unsigned short* hrow = hbf + (long)arow * 64;
        a0 = *(const short8*)(hrow + quad * 8);
        a1 = *(const short8*)(hrow + 32 + quad * 8);
    }

    const short8* wp = (const short8*)Wp;
    f32x4 acc[12];
    #pragma unroll
    for (int ct = 0; ct < 12; ++ct) {
        f32x4 z = {0.f, 0.f, 0.f, 0.f};
        short8 w0 = wp[(ct * 2 + 0) * 64 + lane];
        short8 w1 = wp[(ct * 2 + 1) * 64 + lane];
        z = __builtin_amdgcn_mfma_f32_16x16x32_bf16(a0, w0, z, 0, 0, 0);
        z = __builtin_amdgcn_mfma_f32_16x16x32_bf16(a1, w1, z, 0, 0, 0);
        acc[ct] = z;
    }

    #pragma unroll
    for (int ct = 0; ct < 12; ++ct) {
        int col = ct * 16 + lm;
        unsigned short* dstp = (ct < 4) ? abf : (ct < 8) ? ubf : vbf;
        int lcol = col & 63;
        #pragma unroll
        for (int r = 0; r < 4; ++r) {
            int g = row_base + quad * 4 + r;
            if (g < n) dstp[(long)g * 64 + lcol] = f2b(acc[ct][r]);
        }
    }
}

// ---------------------------------------------------------------------------
// CSR gather + elementwise output tail. One wave per node; lane = (edge
// group g, feature quad f); 512 B per load instr; xor-shuffle reduce; then
// out = relu(S' + deg*(row1 - u) + v + row3) written directly as h (or fp32).
__global__ __launch_bounds__(256) void gather_out_kernel(
    const int* __restrict__ off, const int* __restrict__ csr,
    const unsigned short* __restrict__ abf,
    const unsigned short* __restrict__ ubf,
    const unsigned short* __restrict__ vbf,
    const float* __restrict__ rows,
    float* __restrict__ out_f, unsigned short* __restrict__ out_b, int last)
{
    int node = blockIdx.x * 4 + (threadIdx.x >> 6);
    int lane = threadIdx.x & 63;
    const int g = lane >> 4;
    const int f = (lane & 15) * 4;
    int beg = off[node], end = off[node + 1];
    float deg = (float)(end - beg);
    float ax = 0.f, ay = 0.f, az = 0.f, aw = 0.f;
    int j = beg;
    for (; j + 8 <= end; j += 8) {
        int s0 = csr[j + g], s1 = csr[j + 4 + g];
        ushort4 v0 = *(const ushort4*)(abf + (long)s0 * 64 + f);
        ushort4 v1 = *(const ushort4*)(abf + (long)s1 * 64 + f);
        ax += b2f(v0.x) + b2f(v1.x);
        ay += b2f(v0.y) + b2f(v1.y);
        az += b2f(v0.z) + b2f(v1.z);
        aw += b2f(v0.w) + b2f(v1.w);
    }
    for (; j < end; j += 4) {
        int jj = j + g;
        if (jj < end) {
            int s0 = csr[jj];
            ushort4 v0 = *(const ushort4*)(abf + (long)s0 * 64 + f);
            ax += b2f(v0.x); ay += b2f(v0.y); az += b2f(v0.z); aw += b2f(v0.w);
        }
    }
    #pragma unroll
    for (int m = 16; m < 64; m <<= 1) {
        ax += __shfl_xor(ax, m, 64);
        ay += __shfl_xor(ay, m, 64);
        az += __shfl_xor(az, m, 64);
        aw += __shfl_xor(aw, m, 64);
    }
    if (g == 0) {
        ushort4 uv = *(const ushort4*)(ubf + (long)node * 64 + f);
        ushort4 vv = *(const ushort4*)(vbf + (long)node * 64 + f);
        float4 r1 = *(const float4*)(rows + f);
        float4 r3 = *(const float4*)(rows + 64 + f);
        float o0 = fmaxf(ax + deg * (r1.x - b2f(uv.x)) + b2f(vv.x) + r3.x, 0.f);
        float o1 = fmaxf(ay + deg * (r1.y - b2f(uv.y)) + b2f(vv.y) + r3.y, 0.f);
        float o2 = fmaxf(az + deg * (r1.z - b2f(uv.z)) + b2f(vv.z) + r3.z, 0.f);
        float o3 = fmaxf(aw + deg * (r1.w - b2f(uv.w)) + b2f(vv.w) + r3.w, 0.f);
        if (last) {
            float4 o = {o0, o1, o2, o3};
            *(float4*)(out_f + (long)node * 64 + f) = o;
        } else {
            ushort4 o;
            o.x = f2b(o0); o.y = f2b(o1); o.z = f2b(o2); o.w = f2b(o3);
            *(ushort4*)(out_b + (long)node * 64 + f) = o;
        }
    }
}

// ---------------------------------------------------------------------------
extern "C" void kernel_launch(void* const* d_in, const int* in_sizes, int n_in,
                              void* d_out, int out_size, void* d_ws, size_t ws_size,
                              hipStream_t stream) {
    const float* x  = (const float*)d_in[0];
    const int*   ei = (const int*)d_in[1];
    const int*   src = ei;
    const int*   dst = ei + N_EDGES;

    char* wsb = (char*)d_ws;
    unsigned short* hist_part = (unsigned short*)(wsb);         // 12.8 MB
    unsigned short* abf  = (unsigned short*)(wsb + 12800000);   // 6.4 MB
    unsigned short* ubf  = (unsigned short*)(wsb + 19200000);   // 6.4 MB
    unsigned short* vbf  = (unsigned short*)(wsb + 25600000);   // 6.4 MB
    unsigned short* h1   = (unsigned short*)(wsb + 32000000);   // 6.4 MB
    unsigned short* Wp   = (unsigned short*)(wsb + 38400000);   // 72 KB
    float*          rows = (float*)(wsb + 38500000);            // 1.5 KB
    int* off  = (int*)(wsb + 38600000);                         // N_NODES + 1
    int* bsum = off + N_NODES + 1;
    int* boff = bsum + SCAN_NB;
    int* csr  = boff + SCAN_NB;                                 // N_EDGES

    const int NBLK = (N_NODES + 63) / 64;    // 782

    // ---- CSR build: zero global atomics ----
    histp_kernel<<<NCHUNK * NRANGE, 256, 0, stream>>>(dst, hist_part);
    scanA2_kernel<<<SCAN_NB, 256, 0, stream>>>(hist_part, off, bsum);
    scanB_kernel<<<1, 256, 0, stream>>>(bsum, boff, off);
    scanC_kernel<<<SCAN_NB, 256, 0, stream>>>(boff, off);
    fillp_kernel<<<NCHUNK * NRANGE, 256, 0, stream>>>(src, dst, off, hist_part, csr);

    // ---- weight-product packing (W1@Wl, W2@Wl, W3@Wl + bias rows) ----
    AllPtrs ap;
    for (int l = 0; l < 3; ++l) {
        int base = 2 + l * 7;
        ap.l[l].W1 = (const float*)d_in[base + 0];
        ap.l[l].b1 = (const float*)d_in[base + 1];
        ap.l[l].W2 = (const float*)d_in[base + 2];
        ap.l[l].W3 = (const float*)d_in[base + 3];
        ap.l[l].b3 = (const float*)d_in[base + 4];
        ap.l[l].Wl = (const float*)d_in[base + 5];
        ap.l[l].bl = (const float*)d_in[base + 6];
    }
    pack_mm_kernel<<<36, 256, 0, stream>>>(ap, Wp, rows);

    const unsigned short* hin = nullptr;   // layer 0 reads x directly
    for (int l = 0; l < 3; ++l) {
        const unsigned short* wp = Wp + l * 12288;
        gemm3_mfma_kernel<<<NBLK, 256, 0, stream>>>(
            hin, (l == 0) ? x : nullptr, wp, abf, ubf, vbf, N_NODES);

        int last = (l == 2);
        gather_out_kernel<<<N_NODES / 4, 256, 0, stream>>>(
            off, csr, abf, ubf, vbf, rows + l * 128,
            (float*)d_out, h1, last);
        hin = h1;
    }
}